// Round 2
// baseline (330.036 us; speedup 1.0000x reference)
//
#include <hip/hip_runtime.h>
#include <math.h>

// Match numpy reference numerics exactly: no FMA contraction anywhere.
// Matching decisions (argmax ties, ov<0.5 threshold) rest on bit-exact floats.
#pragma clang fp contract(off)

// Problem constants (match reference)
#define BB      256
#define PP      3249         // 19*19*9
#define NCLS    21
#define NOBJ    12
#define CELLS   361          // 19*19
#define SORTN   4096         // next pow2 >= PP
#define THRESH_ 0.5f

// d_out layout (float32): [0]=loss_l/N, [1]=loss_c/N,
// [2 .. 2+BB*CELLS) = conf_t_featuremap, [2+BB*CELLS .. 2+2*BB*CELLS) = have_centerloss

__global__ __launch_bounds__(256) void match_kernel(
    const float* __restrict__ loc, const float* __restrict__ conf,
    const float* __restrict__ priors, const float* __restrict__ targets,
    int* __restrict__ conf_t, float* __restrict__ ce_out,
    int* __restrict__ numpos, double* __restrict__ lossl)
{
    const int b = blockIdx.x, tid = threadIdx.x;
    __shared__ float s_tx1[NOBJ], s_ty1[NOBJ], s_tx2[NOBJ], s_ty2[NOBJ];
    __shared__ float s_area_t[NOBJ];
    __shared__ int   s_label[NOBJ];
    __shared__ float s_bov[PP];
    __shared__ short s_bidx[PP];
    __shared__ int   s_bpi[NOBJ];
    __shared__ float s_rov[256];
    __shared__ int   s_ridx[256];
    __shared__ double s_rd[256];
    __shared__ int    s_ri[256];

    if (tid < NOBJ) {
        const float* t = targets + ((size_t)b * NOBJ + tid) * 5;
        float x1 = t[0], y1 = t[1], x2 = t[2], y2 = t[3];
        s_tx1[tid] = x1; s_ty1[tid] = y1; s_tx2[tid] = x2; s_ty2[tid] = y2;
        s_label[tid] = (int)t[4];
        s_area_t[tid] = (x2 - x1) * (y2 - y1);
    }
    __syncthreads();

    // Pass 1: IoU; per-prior best truth (first-max), per-truth best prior (first-max)
    float l_bov[NOBJ];
    int   l_bidx[NOBJ];
#pragma unroll
    for (int j = 0; j < NOBJ; ++j) { l_bov[j] = -1.0f; l_bidx[j] = 0x7FFFFFFF; }

    for (int p = tid; p < PP; p += 256) {
        float cx = priors[4*p+0], cy = priors[4*p+1], w = priors[4*p+2], h = priors[4*p+3];
        float px1 = cx - w / 2.0f, py1 = cy - h / 2.0f;
        float px2 = cx + w / 2.0f, py2 = cy + h / 2.0f;
        float area_p = (px2 - px1) * (py2 - py1);
        float bov = -1.0f; int bidx = 0;
#pragma unroll
        for (int j = 0; j < NOBJ; ++j) {
            float ltx = fmaxf(s_tx1[j], px1);
            float lty = fmaxf(s_ty1[j], py1);
            float rbx = fminf(s_tx2[j], px2);
            float rby = fminf(s_ty2[j], py2);
            float iw = fmaxf(rbx - ltx, 0.0f);
            float ih = fmaxf(rby - lty, 0.0f);
            float inter = iw * ih;
            float iou = inter / ((s_area_t[j] + area_p) - inter);
            if (iou > bov) { bov = iou; bidx = j; }              // first max over truths
            if (iou > l_bov[j]) { l_bov[j] = iou; l_bidx[j] = p; } // first max over priors (this thread)
        }
        s_bov[p] = bov;
        s_bidx[p] = (short)bidx;
    }
    __syncthreads();

    // Cross-thread reduce per-truth best prior (ties -> smaller prior index)
    for (int j = 0; j < NOBJ; ++j) {
        s_rov[tid] = l_bov[j]; s_ridx[tid] = l_bidx[j];
        __syncthreads();
        for (int s = 128; s > 0; s >>= 1) {
            if (tid < s) {
                float o2 = s_rov[tid + s]; int i2 = s_ridx[tid + s];
                if (o2 > s_rov[tid] || (o2 == s_rov[tid] && i2 < s_ridx[tid])) {
                    s_rov[tid] = o2; s_ridx[tid] = i2;
                }
            }
            __syncthreads();
        }
        if (tid == 0) s_bpi[j] = s_ridx[0];
        __syncthreads();
    }

    // Pass 2: conf_t, CE, smooth-L1 partial
    int my_pos = 0;
    double my_lossl = 0.0;
    for (int p = tid; p < PP; p += 256) {
        int jov = -1;
#pragma unroll
        for (int j = 0; j < NOBJ; ++j) if (s_bpi[j] == p) jov = j;  // last-wins on duplicates
        int idx; float ov;
        if (jov >= 0) { idx = jov; ov = 2.0f; }
        else          { idx = (int)s_bidx[p]; ov = s_bov[p]; }
        int c = (ov < THRESH_) ? 0 : (s_label[idx] + 1);
        conf_t[(size_t)b * PP + p] = c;

        const float* cd = conf + ((size_t)b * PP + p) * NCLS;
        float m = cd[0];
#pragma unroll
        for (int k = 1; k < NCLS; ++k) m = fmaxf(m, cd[k]);
        float s = 0.0f;
#pragma unroll
        for (int k = 0; k < NCLS; ++k) s += expf(cd[k] - m);
        float lse = logf(s) + m;
        ce_out[(size_t)b * PP + p] = lse - cd[c];

        if (c > 0) {
            ++my_pos;
            float cx = priors[4*p+0], cy = priors[4*p+1], w = priors[4*p+2], h = priors[4*p+3];
            float m0 = s_tx1[idx], m1 = s_ty1[idx], m2 = s_tx2[idx], m3 = s_ty2[idx];
            float g0 = ((m0 + m2) / 2.0f - cx) / (0.1f * w);
            float g1 = ((m1 + m3) / 2.0f - cy) / (0.1f * h);
            float g2 = logf((m2 - m0) / w) / 0.2f;
            float g3 = logf((m3 - m1) / h) / 0.2f;
            const float* ld = loc + ((size_t)b * PP + p) * 4;
            float d0 = ld[0] - g0, d1 = ld[1] - g1, d2 = ld[2] - g2, d3 = ld[3] - g3;
            float a0 = fabsf(d0), a1 = fabsf(d1), a2 = fabsf(d2), a3 = fabsf(d3);
            my_lossl += (double)((a0 < 1.0f) ? 0.5f * d0 * d0 : a0 - 0.5f);
            my_lossl += (double)((a1 < 1.0f) ? 0.5f * d1 * d1 : a1 - 0.5f);
            my_lossl += (double)((a2 < 1.0f) ? 0.5f * d2 * d2 : a2 - 0.5f);
            my_lossl += (double)((a3 < 1.0f) ? 0.5f * d3 * d3 : a3 - 0.5f);
        }
    }
    s_rd[tid] = my_lossl; s_ri[tid] = my_pos;
    __syncthreads();
    for (int s = 128; s > 0; s >>= 1) {
        if (tid < s) { s_rd[tid] += s_rd[tid + s]; s_ri[tid] += s_ri[tid + s]; }
        __syncthreads();
    }
    if (tid == 0) { lossl[b] = s_rd[0]; numpos[b] = s_ri[0]; }
}

// Hard-negative mining via exact bitonic sort of (value, ~index) keys.
// Key = (float_bits(loss_c_mine) << 32) | (0xFFFFFFFF - p). All values >= 0 so
// the float bit pattern is monotone; larger key == larger value, ties -> smaller p.
// Top num_neg keys == reference's stable argsort top-k, exactly.
__global__ __launch_bounds__(256) void mine_kernel(
    const int* __restrict__ conf_t, const float* __restrict__ ce,
    const int* __restrict__ numpos, double* __restrict__ lossc,
    float* __restrict__ out)
{
    const int b = blockIdx.x, tid = threadIdx.x;
    __shared__ unsigned long long s_key[SORTN];
    __shared__ unsigned char s_sel[SORTN];
    __shared__ double s_rd[256];

    const int np = numpos[b];
    const int nneg = min(3 * np, PP - 1);

    for (int i = tid; i < SORTN; i += 256) {
        unsigned long long key = 0ull;   // padding sorts below all real entries
        if (i < PP) {
            int c = conf_t[(size_t)b * PP + i];
            float v = (c > 0) ? 0.0f : ce[(size_t)b * PP + i];
            unsigned int vb = __float_as_uint(v);
            key = ((unsigned long long)vb << 32) | (unsigned int)(0xFFFFFFFFu - (unsigned int)i);
        }
        s_key[i] = key;
        s_sel[i] = 0;
    }
    __syncthreads();

    // Bitonic sort ascending; largest nneg end up at the tail.
    for (int k = 2; k <= SORTN; k <<= 1) {
        for (int j = k >> 1; j > 0; j >>= 1) {
            for (int i = tid; i < SORTN; i += 256) {
                int ij = i ^ j;
                if (ij > i) {
                    bool up = ((i & k) == 0);
                    unsigned long long a = s_key[i], bb2 = s_key[ij];
                    if (up ? (a > bb2) : (a < bb2)) { s_key[i] = bb2; s_key[ij] = a; }
                }
            }
            __syncthreads();
        }
    }

    for (int r = tid; r < nneg; r += 256) {
        unsigned long long key = s_key[SORTN - 1 - r];
        unsigned int p = 0xFFFFFFFFu - (unsigned int)(key & 0xFFFFFFFFull);
        s_sel[p] = 1;
    }
    __syncthreads();

    double my_c = 0.0;
    for (int p = tid; p < PP; p += 256) {
        int c = conf_t[(size_t)b * PP + p];
        bool sel = (c > 0) || (s_sel[p] != 0);
        s_sel[p] = sel ? 1 : 0;
        if (sel) my_c += (double)ce[(size_t)b * PP + p];
    }
    __syncthreads();

    // Per-cell outputs
    for (int cI = tid; cI < CELLS; cI += 256) {
        int mc = 0, hv = 0;
#pragma unroll
        for (int a = 0; a < 9; ++a) {
            int p = cI * 9 + a;
            int cv = conf_t[(size_t)b * PP + p];
            mc = (cv > mc) ? cv : mc;
            hv |= s_sel[p];
        }
        out[2 + (size_t)b * CELLS + cI] = (float)mc;
        out[2 + (size_t)BB * CELLS + (size_t)b * CELLS + cI] = (float)hv;
    }

    s_rd[tid] = my_c;
    __syncthreads();
    for (int s = 128; s > 0; s >>= 1) {
        if (tid < s) s_rd[tid] += s_rd[tid + s];
        __syncthreads();
    }
    if (tid == 0) lossc[b] = s_rd[0];
}

__global__ __launch_bounds__(256) void finalize_kernel(
    const int* __restrict__ numpos, const double* __restrict__ lossl,
    const double* __restrict__ lossc, float* __restrict__ out)
{
    __shared__ double s_l[256], s_c[256];
    __shared__ int s_n[256];
    int tid = threadIdx.x;
    s_n[tid] = numpos[tid];     // BB == 256 == blockDim
    s_l[tid] = lossl[tid];
    s_c[tid] = lossc[tid];
    __syncthreads();
    for (int s = 128; s > 0; s >>= 1) {
        if (tid < s) { s_n[tid] += s_n[tid + s]; s_l[tid] += s_l[tid + s]; s_c[tid] += s_c[tid + s]; }
        __syncthreads();
    }
    if (tid == 0) {
        double N = (double)s_n[0];
        out[0] = (float)(s_l[0] / N);
        out[1] = (float)(s_c[0] / N);
    }
}

extern "C" void kernel_launch(void* const* d_in, const int* in_sizes, int n_in,
                              void* d_out, int out_size, void* d_ws, size_t ws_size,
                              hipStream_t stream) {
    const float* loc     = (const float*)d_in[0];  // (B, P, 4)
    const float* conf    = (const float*)d_in[1];  // (B, P, 21)
    const float* priors  = (const float*)d_in[2];  // (P, 4)
    const float* targets = (const float*)d_in[3];  // (B, 12, 5)
    float* out = (float*)d_out;

    // Workspace carve-up (8-byte aligned first)
    double* ws_lossl = (double*)d_ws;                 // BB
    double* ws_lossc = ws_lossl + BB;                 // BB
    int*    ws_numpos = (int*)(ws_lossc + BB);        // BB
    int*    ws_conf   = ws_numpos + BB;               // BB*PP
    float*  ws_ce     = (float*)(ws_conf + (size_t)BB * PP); // BB*PP

    hipLaunchKernelGGL(match_kernel, dim3(BB), dim3(256), 0, stream,
                       loc, conf, priors, targets, ws_conf, ws_ce, ws_numpos, ws_lossl);
    hipLaunchKernelGGL(mine_kernel, dim3(BB), dim3(256), 0, stream,
                       ws_conf, ws_ce, ws_numpos, ws_lossc, out);
    hipLaunchKernelGGL(finalize_kernel, dim3(1), dim3(256), 0, stream,
                       ws_numpos, ws_lossl, ws_lossc, out);
}

// Round 3
// 212.450 us; speedup vs baseline: 1.5535x; 1.5535x over previous
//
#include <hip/hip_runtime.h>
#include <math.h>

// Match numpy reference numerics exactly: no FMA contraction anywhere.
// Matching decisions (argmax ties, ov<0.5 threshold) rest on bit-exact floats.
#pragma clang fp contract(off)

// Problem constants (match reference)
#define BB      256
#define PP      3249         // 19*19*9
#define NCLS    21
#define NOBJ    12
#define CELLS   361          // 19*19
#define SORTN   4096         // next pow2 >= PP
#define THRESH_ 0.5f

// d_out layout (float32): [0]=loss_l/N, [1]=loss_c/N,
// [2 .. 2+BB*CELLS) = conf_t_featuremap, [2+BB*CELLS .. 2+2*BB*CELLS) = have_centerloss

// ---------------------------------------------------------------------------
// Kernel A: matching only (IoU, forced matches, conf_t, loss_l, numpos).
// One block per batch; CE moved out so this is a small VALU job.
// ---------------------------------------------------------------------------
__global__ __launch_bounds__(256) void match_kernel(
    const float* __restrict__ loc,
    const float* __restrict__ priors, const float* __restrict__ targets,
    int* __restrict__ conf_t,
    int* __restrict__ numpos, double* __restrict__ lossl)
{
    const int b = blockIdx.x, tid = threadIdx.x;
    __shared__ float s_tx1[NOBJ], s_ty1[NOBJ], s_tx2[NOBJ], s_ty2[NOBJ];
    __shared__ float s_area_t[NOBJ];
    __shared__ int   s_label[NOBJ];
    __shared__ float s_bov[PP];
    __shared__ short s_bidx[PP];
    __shared__ int   s_bpi[NOBJ];
    __shared__ float s_rov[256];
    __shared__ int   s_ridx[256];
    __shared__ double s_rd[256];
    __shared__ int    s_ri[256];

    if (tid < NOBJ) {
        const float* t = targets + ((size_t)b * NOBJ + tid) * 5;
        float x1 = t[0], y1 = t[1], x2 = t[2], y2 = t[3];
        s_tx1[tid] = x1; s_ty1[tid] = y1; s_tx2[tid] = x2; s_ty2[tid] = y2;
        s_label[tid] = (int)t[4];
        s_area_t[tid] = (x2 - x1) * (y2 - y1);
    }
    __syncthreads();

    // Pass 1: IoU; per-prior best truth (first-max), per-truth best prior (first-max)
    float l_bov[NOBJ];
    int   l_bidx[NOBJ];
#pragma unroll
    for (int j = 0; j < NOBJ; ++j) { l_bov[j] = -1.0f; l_bidx[j] = 0x7FFFFFFF; }

    for (int p = tid; p < PP; p += 256) {
        float cx = priors[4*p+0], cy = priors[4*p+1], w = priors[4*p+2], h = priors[4*p+3];
        float px1 = cx - w / 2.0f, py1 = cy - h / 2.0f;
        float px2 = cx + w / 2.0f, py2 = cy + h / 2.0f;
        float area_p = (px2 - px1) * (py2 - py1);
        float bov = -1.0f; int bidx = 0;
#pragma unroll
        for (int j = 0; j < NOBJ; ++j) {
            float ltx = fmaxf(s_tx1[j], px1);
            float lty = fmaxf(s_ty1[j], py1);
            float rbx = fminf(s_tx2[j], px2);
            float rby = fminf(s_ty2[j], py2);
            float iw = fmaxf(rbx - ltx, 0.0f);
            float ih = fmaxf(rby - lty, 0.0f);
            float inter = iw * ih;
            float iou = inter / ((s_area_t[j] + area_p) - inter);
            if (iou > bov) { bov = iou; bidx = j; }              // first max over truths
            if (iou > l_bov[j]) { l_bov[j] = iou; l_bidx[j] = p; } // first max over priors (this thread)
        }
        s_bov[p] = bov;
        s_bidx[p] = (short)bidx;
    }
    __syncthreads();

    // Cross-thread reduce per-truth best prior (ties -> smaller prior index)
    for (int j = 0; j < NOBJ; ++j) {
        s_rov[tid] = l_bov[j]; s_ridx[tid] = l_bidx[j];
        __syncthreads();
        for (int s = 128; s > 0; s >>= 1) {
            if (tid < s) {
                float o2 = s_rov[tid + s]; int i2 = s_ridx[tid + s];
                if (o2 > s_rov[tid] || (o2 == s_rov[tid] && i2 < s_ridx[tid])) {
                    s_rov[tid] = o2; s_ridx[tid] = i2;
                }
            }
            __syncthreads();
        }
        if (tid == 0) s_bpi[j] = s_ridx[0];
        __syncthreads();
    }

    // Pass 2: conf_t + smooth-L1 partial (loc loaded only for positives)
    int my_pos = 0;
    double my_lossl = 0.0;
    for (int p = tid; p < PP; p += 256) {
        int jov = -1;
#pragma unroll
        for (int j = 0; j < NOBJ; ++j) if (s_bpi[j] == p) jov = j;  // last-wins on duplicates
        int idx; float ov;
        if (jov >= 0) { idx = jov; ov = 2.0f; }
        else          { idx = (int)s_bidx[p]; ov = s_bov[p]; }
        int c = (ov < THRESH_) ? 0 : (s_label[idx] + 1);
        conf_t[(size_t)b * PP + p] = c;

        if (c > 0) {
            ++my_pos;
            float cx = priors[4*p+0], cy = priors[4*p+1], w = priors[4*p+2], h = priors[4*p+3];
            float m0 = s_tx1[idx], m1 = s_ty1[idx], m2 = s_tx2[idx], m3 = s_ty2[idx];
            float g0 = ((m0 + m2) / 2.0f - cx) / (0.1f * w);
            float g1 = ((m1 + m3) / 2.0f - cy) / (0.1f * h);
            float g2 = logf((m2 - m0) / w) / 0.2f;
            float g3 = logf((m3 - m1) / h) / 0.2f;
            const float* ld = loc + ((size_t)b * PP + p) * 4;
            float d0 = ld[0] - g0, d1 = ld[1] - g1, d2 = ld[2] - g2, d3 = ld[3] - g3;
            float a0 = fabsf(d0), a1 = fabsf(d1), a2 = fabsf(d2), a3 = fabsf(d3);
            my_lossl += (double)((a0 < 1.0f) ? 0.5f * d0 * d0 : a0 - 0.5f);
            my_lossl += (double)((a1 < 1.0f) ? 0.5f * d1 * d1 : a1 - 0.5f);
            my_lossl += (double)((a2 < 1.0f) ? 0.5f * d2 * d2 : a2 - 0.5f);
            my_lossl += (double)((a3 < 1.0f) ? 0.5f * d3 * d3 : a3 - 0.5f);
        }
    }
    s_rd[tid] = my_lossl; s_ri[tid] = my_pos;
    __syncthreads();
    for (int s = 128; s > 0; s >>= 1) {
        if (tid < s) { s_rd[tid] += s_rd[tid + s]; s_ri[tid] += s_ri[tid + s]; }
        __syncthreads();
    }
    if (tid == 0) { lossl[b] = s_rd[0]; numpos[b] = s_ri[0]; }
}

// ---------------------------------------------------------------------------
// Kernel B: cross-entropy per (b,p) row — the 70 MB sweep, full occupancy.
// One thread per row; op order identical to the previously-passing version.
// ---------------------------------------------------------------------------
__global__ __launch_bounds__(256) void ce_kernel(
    const float* __restrict__ conf, const int* __restrict__ conf_t,
    float* __restrict__ ce_out)
{
    const int r = blockIdx.x * 256 + threadIdx.x;
    if (r >= BB * PP) return;
    const float* cd = conf + (size_t)r * NCLS;
    float m = cd[0];
#pragma unroll
    for (int k = 1; k < NCLS; ++k) m = fmaxf(m, cd[k]);
    float s = 0.0f;
#pragma unroll
    for (int k = 0; k < NCLS; ++k) s += expf(cd[k] - m);
    float lse = logf(s) + m;
    int c = conf_t[r];
    ce_out[r] = lse - cd[c];
}

// ---------------------------------------------------------------------------
// Kernel C: hard-negative mining via exact bitonic sort of (value, ~index)
// keys, 1024 threads/block for latency hiding across the 78 barrier phases.
// Key = (float_bits(loss_c_mine) << 32) | (0xFFFFFFFF - p). All values >= 0 so
// the float bit pattern is monotone; larger key == larger value, ties -> smaller p.
// ---------------------------------------------------------------------------
__global__ __launch_bounds__(1024) void mine_kernel(
    const int* __restrict__ conf_t, const float* __restrict__ ce,
    const int* __restrict__ numpos, double* __restrict__ lossc,
    float* __restrict__ out)
{
    const int b = blockIdx.x, tid = threadIdx.x;
    __shared__ unsigned long long s_key[SORTN];
    __shared__ unsigned char s_sel[SORTN];
    __shared__ double s_rd[1024];

    const int np = numpos[b];
    const int nneg = min(3 * np, PP - 1);

    for (int i = tid; i < SORTN; i += 1024) {
        unsigned long long key = 0ull;   // padding sorts below all real entries
        if (i < PP) {
            int c = conf_t[(size_t)b * PP + i];
            float v = (c > 0) ? 0.0f : ce[(size_t)b * PP + i];
            unsigned int vb = __float_as_uint(v);
            key = ((unsigned long long)vb << 32) | (unsigned int)(0xFFFFFFFFu - (unsigned int)i);
        }
        s_key[i] = key;
        s_sel[i] = 0;
    }
    __syncthreads();

    // Bitonic sort ascending; largest nneg end up at the tail.
    for (int k = 2; k <= SORTN; k <<= 1) {
        for (int j = k >> 1; j > 0; j >>= 1) {
            for (int i = tid; i < SORTN; i += 1024) {
                int ij = i ^ j;
                if (ij > i) {
                    bool up = ((i & k) == 0);
                    unsigned long long a = s_key[i], bb2 = s_key[ij];
                    if (up ? (a > bb2) : (a < bb2)) { s_key[i] = bb2; s_key[ij] = a; }
                }
            }
            __syncthreads();
        }
    }

    for (int r = tid; r < nneg; r += 1024) {
        unsigned long long key = s_key[SORTN - 1 - r];
        unsigned int p = 0xFFFFFFFFu - (unsigned int)(key & 0xFFFFFFFFull);
        s_sel[p] = 1;
    }
    __syncthreads();

    double my_c = 0.0;
    for (int p = tid; p < PP; p += 1024) {
        int c = conf_t[(size_t)b * PP + p];
        bool sel = (c > 0) || (s_sel[p] != 0);
        s_sel[p] = sel ? 1 : 0;
        if (sel) my_c += (double)ce[(size_t)b * PP + p];
    }
    __syncthreads();

    // Per-cell outputs
    for (int cI = tid; cI < CELLS; cI += 1024) {
        int mc = 0, hv = 0;
#pragma unroll
        for (int a = 0; a < 9; ++a) {
            int p = cI * 9 + a;
            int cv = conf_t[(size_t)b * PP + p];
            mc = (cv > mc) ? cv : mc;
            hv |= s_sel[p];
        }
        out[2 + (size_t)b * CELLS + cI] = (float)mc;
        out[2 + (size_t)BB * CELLS + (size_t)b * CELLS + cI] = (float)hv;
    }

    s_rd[tid] = my_c;
    __syncthreads();
    for (int s = 512; s > 0; s >>= 1) {
        if (tid < s) s_rd[tid] += s_rd[tid + s];
        __syncthreads();
    }
    if (tid == 0) lossc[b] = s_rd[0];
}

__global__ __launch_bounds__(256) void finalize_kernel(
    const int* __restrict__ numpos, const double* __restrict__ lossl,
    const double* __restrict__ lossc, float* __restrict__ out)
{
    __shared__ double s_l[256], s_c[256];
    __shared__ int s_n[256];
    int tid = threadIdx.x;
    s_n[tid] = numpos[tid];     // BB == 256 == blockDim
    s_l[tid] = lossl[tid];
    s_c[tid] = lossc[tid];
    __syncthreads();
    for (int s = 128; s > 0; s >>= 1) {
        if (tid < s) { s_n[tid] += s_n[tid + s]; s_l[tid] += s_l[tid + s]; s_c[tid] += s_c[tid + s]; }
        __syncthreads();
    }
    if (tid == 0) {
        double N = (double)s_n[0];
        out[0] = (float)(s_l[0] / N);
        out[1] = (float)(s_c[0] / N);
    }
}

extern "C" void kernel_launch(void* const* d_in, const int* in_sizes, int n_in,
                              void* d_out, int out_size, void* d_ws, size_t ws_size,
                              hipStream_t stream) {
    const float* loc     = (const float*)d_in[0];  // (B, P, 4)
    const float* conf    = (const float*)d_in[1];  // (B, P, 21)
    const float* priors  = (const float*)d_in[2];  // (P, 4)
    const float* targets = (const float*)d_in[3];  // (B, 12, 5)
    float* out = (float*)d_out;

    // Workspace carve-up (8-byte aligned first)
    double* ws_lossl = (double*)d_ws;                 // BB
    double* ws_lossc = ws_lossl + BB;                 // BB
    int*    ws_numpos = (int*)(ws_lossc + BB);        // BB
    int*    ws_conf   = ws_numpos + BB;               // BB*PP
    float*  ws_ce     = (float*)(ws_conf + (size_t)BB * PP); // BB*PP

    hipLaunchKernelGGL(match_kernel, dim3(BB), dim3(256), 0, stream,
                       loc, priors, targets, ws_conf, ws_numpos, ws_lossl);
    hipLaunchKernelGGL(ce_kernel, dim3((BB * PP + 255) / 256), dim3(256), 0, stream,
                       conf, ws_conf, ws_ce);
    hipLaunchKernelGGL(mine_kernel, dim3(BB), dim3(1024), 0, stream,
                       ws_conf, ws_ce, ws_numpos, ws_lossc, out);
    hipLaunchKernelGGL(finalize_kernel, dim3(1), dim3(256), 0, stream,
                       ws_numpos, ws_lossl, ws_lossc, out);
}

// Round 4
// 149.199 us; speedup vs baseline: 2.2121x; 1.4239x over previous
//
#include <hip/hip_runtime.h>
#include <math.h>

// Match numpy reference numerics exactly: no FMA contraction anywhere.
// Matching decisions (argmax ties, ov<0.5 threshold) rest on bit-exact floats.
#pragma clang fp contract(off)

#define BB      256
#define PP      3249         // 19*19*9
#define NCLS    21
#define NOBJ    12
#define CELLS   361          // 19*19
#define THRESH_ 0.5f

// d_out layout (float32): [0]=loss_l/N, [1]=loss_c/N,
// [2 .. 2+BB*CELLS) = conf_t_featuremap, [2+BB*CELLS .. 2+2*BB*CELLS) = have_centerloss

// ---------------------------------------------------------------------------
// Kernel A: matching (IoU, forced matches, conf_t, loss_l, numpos).
// 1024 threads/block, wave-shuffle reductions (max with min-index tiebreak is
// associative+commutative so butterfly order is safe).
// ---------------------------------------------------------------------------
__global__ __launch_bounds__(1024) void match_kernel(
    const float* __restrict__ loc,
    const float* __restrict__ priors, const float* __restrict__ targets,
    int* __restrict__ conf_t,
    int* __restrict__ numpos, double* __restrict__ lossl)
{
    const int b = blockIdx.x, tid = threadIdx.x;
    const int lane = tid & 63, wid = tid >> 6;   // 16 waves
    __shared__ float s_tx1[NOBJ], s_ty1[NOBJ], s_tx2[NOBJ], s_ty2[NOBJ];
    __shared__ float s_area_t[NOBJ];
    __shared__ int   s_label[NOBJ];
    __shared__ float s_bov[PP];
    __shared__ short s_bidx[PP];
    __shared__ int   s_bpi[NOBJ];
    __shared__ float s_wov[NOBJ][16];
    __shared__ int   s_widx[NOBJ][16];
    __shared__ double s_pl[16];
    __shared__ int    s_pn[16];

    if (tid < NOBJ) {
        const float* t = targets + ((size_t)b * NOBJ + tid) * 5;
        float x1 = t[0], y1 = t[1], x2 = t[2], y2 = t[3];
        s_tx1[tid] = x1; s_ty1[tid] = y1; s_tx2[tid] = x2; s_ty2[tid] = y2;
        s_label[tid] = (int)t[4];
        s_area_t[tid] = (x2 - x1) * (y2 - y1);
    }
    __syncthreads();

    // Pass 1: IoU; per-prior best truth (first-max); per-truth best prior.
    float l_bov[NOBJ];
    int   l_bidx[NOBJ];
#pragma unroll
    for (int j = 0; j < NOBJ; ++j) { l_bov[j] = -1.0f; l_bidx[j] = 0x7FFFFFFF; }

    for (int p = tid; p < PP; p += 1024) {
        float cx = priors[4*p+0], cy = priors[4*p+1], w = priors[4*p+2], h = priors[4*p+3];
        float px1 = cx - w / 2.0f, py1 = cy - h / 2.0f;
        float px2 = cx + w / 2.0f, py2 = cy + h / 2.0f;
        float area_p = (px2 - px1) * (py2 - py1);
        float bov = -1.0f; int bidx = 0;
#pragma unroll
        for (int j = 0; j < NOBJ; ++j) {
            float ltx = fmaxf(s_tx1[j], px1);
            float lty = fmaxf(s_ty1[j], py1);
            float rbx = fminf(s_tx2[j], px2);
            float rby = fminf(s_ty2[j], py2);
            float iw = fmaxf(rbx - ltx, 0.0f);
            float ih = fmaxf(rby - lty, 0.0f);
            float inter = iw * ih;
            float iou = inter / ((s_area_t[j] + area_p) - inter);
            if (iou > bov) { bov = iou; bidx = j; }              // first max over truths
            if (iou > l_bov[j]) { l_bov[j] = iou; l_bidx[j] = p; } // best prior for truth j (this thread)
        }
        s_bov[p] = bov;
        s_bidx[p] = (short)bidx;
    }

    // Wave-level butterfly reduce each truth's (ov, idx), ties -> smaller idx.
#pragma unroll
    for (int j = 0; j < NOBJ; ++j) {
        float ov = l_bov[j]; int ix = l_bidx[j];
#pragma unroll
        for (int off = 32; off > 0; off >>= 1) {
            float ov2 = __shfl_xor(ov, off);
            int   ix2 = __shfl_xor(ix, off);
            if (ov2 > ov || (ov2 == ov && ix2 < ix)) { ov = ov2; ix = ix2; }
        }
        if (lane == 0) { s_wov[j][wid] = ov; s_widx[j][wid] = ix; }
    }
    __syncthreads();

    // Combine 16 wave partials per truth (threads 0..11, serial over 16).
    if (tid < NOBJ) {
        float ov = s_wov[tid][0]; int ix = s_widx[tid][0];
#pragma unroll
        for (int w2 = 1; w2 < 16; ++w2) {
            float ov2 = s_wov[tid][w2]; int ix2 = s_widx[tid][w2];
            if (ov2 > ov || (ov2 == ov && ix2 < ix)) { ov = ov2; ix = ix2; }
        }
        s_bpi[tid] = ix;
    }
    __syncthreads();

    // Pass 2: conf_t + smooth-L1 partial (loc loaded only for positives)
    int my_pos = 0;
    double my_lossl = 0.0;
    for (int p = tid; p < PP; p += 1024) {
        int jov = -1;
#pragma unroll
        for (int j = 0; j < NOBJ; ++j) if (s_bpi[j] == p) jov = j;  // last-wins on duplicates
        int idx; float ov;
        if (jov >= 0) { idx = jov; ov = 2.0f; }
        else          { idx = (int)s_bidx[p]; ov = s_bov[p]; }
        int c = (ov < THRESH_) ? 0 : (s_label[idx] + 1);
        conf_t[(size_t)b * PP + p] = c;

        if (c > 0) {
            ++my_pos;
            float cx = priors[4*p+0], cy = priors[4*p+1], w = priors[4*p+2], h = priors[4*p+3];
            float m0 = s_tx1[idx], m1 = s_ty1[idx], m2 = s_tx2[idx], m3 = s_ty2[idx];
            float g0 = ((m0 + m2) / 2.0f - cx) / (0.1f * w);
            float g1 = ((m1 + m3) / 2.0f - cy) / (0.1f * h);
            float g2 = logf((m2 - m0) / w) / 0.2f;
            float g3 = logf((m3 - m1) / h) / 0.2f;
            const float* ld = loc + ((size_t)b * PP + p) * 4;
            float d0 = ld[0] - g0, d1 = ld[1] - g1, d2 = ld[2] - g2, d3 = ld[3] - g3;
            float a0 = fabsf(d0), a1 = fabsf(d1), a2 = fabsf(d2), a3 = fabsf(d3);
            my_lossl += (double)((a0 < 1.0f) ? 0.5f * d0 * d0 : a0 - 0.5f);
            my_lossl += (double)((a1 < 1.0f) ? 0.5f * d1 * d1 : a1 - 0.5f);
            my_lossl += (double)((a2 < 1.0f) ? 0.5f * d2 * d2 : a2 - 0.5f);
            my_lossl += (double)((a3 < 1.0f) ? 0.5f * d3 * d3 : a3 - 0.5f);
        }
    }
    // Wave reduce then 16-partial combine.
#pragma unroll
    for (int off = 32; off > 0; off >>= 1) {
        my_lossl += __shfl_down(my_lossl, off);
        my_pos   += __shfl_down(my_pos, off);
    }
    if (lane == 0) { s_pl[wid] = my_lossl; s_pn[wid] = my_pos; }
    __syncthreads();
    if (tid == 0) {
        double L = 0.0; int n = 0;
#pragma unroll
        for (int w2 = 0; w2 < 16; ++w2) { L += s_pl[w2]; n += s_pn[w2]; }
        lossl[b] = L; numpos[b] = n;
    }
}

// ---------------------------------------------------------------------------
// Kernel B: cross-entropy per (b,p) row — 70 MB sweep at HBM BW.
// 3249 blocks x 256 rows; stage 256x21 floats via coalesced float4 (block base
// offset 256*84 B is 16B-aligned), reduce from LDS (odd stride 21 -> <=2-way
// bank aliasing, free). Op order identical to the passing version.
// ---------------------------------------------------------------------------
__global__ __launch_bounds__(256) void ce_kernel(
    const float* __restrict__ conf, const int* __restrict__ conf_t,
    float* __restrict__ ce_out)
{
    __shared__ float s_row[256 * NCLS];   // 21504 B == 1344 float4
    const int tid = threadIdx.x;
    const size_t base = (size_t)blockIdx.x * 256;      // first row of this block
    const float4* src = (const float4*)(conf + base * NCLS);
    float4* dst = (float4*)s_row;
#pragma unroll
    for (int i = tid; i < 1344; i += 256) dst[i] = src[i];
    __syncthreads();

    const float* cd = s_row + tid * NCLS;
    float m = cd[0];
#pragma unroll
    for (int k = 1; k < NCLS; ++k) m = fmaxf(m, cd[k]);
    float s = 0.0f;
#pragma unroll
    for (int k = 0; k < NCLS; ++k) s += expf(cd[k] - m);
    float lse = logf(s) + m;
    const size_t r = base + tid;
    int c = conf_t[r];
    ce_out[r] = lse - cd[c];
}

// ---------------------------------------------------------------------------
// Kernel C: hard-negative mining via exact 8-bit RADIX SELECT on 64-bit keys.
// Key = (float_bits(loss_c_mine) << 32) | (0xFFFFFFFF - p): all keys distinct,
// larger key == (larger value, then smaller index) — identical ordering to the
// reference's stable argsort. sel = key >= kth_largest marks exactly nneg keys.
// ---------------------------------------------------------------------------
__global__ __launch_bounds__(1024) void mine_kernel(
    const int* __restrict__ conf_t, const float* __restrict__ ce,
    const int* __restrict__ numpos, double* __restrict__ lossc,
    float* __restrict__ out)
{
    const int b = blockIdx.x, tid = threadIdx.x;
    const int lane = tid & 63, wid = tid >> 6;
    __shared__ unsigned long long s_key[PP];    // 25992 B
    __shared__ unsigned char s_ct[PP];          // conf_t (0..21)
    __shared__ unsigned char s_sel[PP];
    __shared__ int s_hist[256];
    __shared__ int s_chosen, s_knext;
    __shared__ double s_part[16];

    const int np = numpos[b];
    const int nneg = min(3 * np, PP - 1);       // >= 3 (forced matches => np >= 1)

    for (int i = tid; i < PP; i += 1024) {
        int c = conf_t[(size_t)b * PP + i];
        float v = (c > 0) ? 0.0f : ce[(size_t)b * PP + i];
        s_key[i] = ((unsigned long long)__float_as_uint(v) << 32)
                 | (unsigned int)(0xFFFFFFFFu - (unsigned int)i);
        s_ct[i] = (unsigned char)c;
    }
    __syncthreads();

    // 8 radix rounds, high digit first. prefix narrows the candidate group;
    // kk = rank (1-based, from the top) of the target key within the group.
    unsigned long long prefix = 0ull, pmask = 0ull;
    int kk = nneg;
    for (int d = 56; d >= 0; d -= 8) {
        if (tid < 256) s_hist[tid] = 0;
        __syncthreads();
        for (int i = tid; i < PP; i += 1024) {
            unsigned long long key = s_key[i];
            if ((key & pmask) == prefix)
                atomicAdd(&s_hist[(int)((key >> d) & 0xFF)], 1);
        }
        __syncthreads();
        if (tid < 64) {   // wave 0: find bin where cumulative (from 255 down) crosses kk
            int h0 = s_hist[4*lane+0], h1 = s_hist[4*lane+1];
            int h2 = s_hist[4*lane+2], h3 = s_hist[4*lane+3];
            int ls = h0 + h1 + h2 + h3;
            int x = ls;                       // inclusive suffix sum over lanes
#pragma unroll
            for (int off = 1; off < 64; off <<= 1) {
                int y = __shfl_down(x, off);
                if (lane + off < 64) x += y;
            }
            int excl = x - ls;                // sum over lanes > lane
            // bins high->low within lane: 4l+3, 4l+2, 4l+1, 4l
            int cb3 = excl;
            int cb2 = cb3 + h3;
            int cb1 = cb2 + h2;
            int cb0 = cb1 + h1;
            if (cb3 < kk && kk <= cb3 + h3) { s_chosen = 4*lane+3; s_knext = kk - cb3; }
            if (cb2 < kk && kk <= cb2 + h2) { s_chosen = 4*lane+2; s_knext = kk - cb2; }
            if (cb1 < kk && kk <= cb1 + h1) { s_chosen = 4*lane+1; s_knext = kk - cb1; }
            if (cb0 < kk && kk <= cb0 + h0) { s_chosen = 4*lane+0; s_knext = kk - cb0; }
        }
        __syncthreads();
        prefix |= ((unsigned long long)(unsigned int)s_chosen) << d;
        pmask  |= 0xFFull << d;
        kk = s_knext;
        __syncthreads();   // protect s_chosen/s_knext before next round's writes
    }
    const unsigned long long kth = prefix;   // exact nneg-th largest key

    // Selection + loss_c sum. Negatives' CE comes from the key's upper bits.
    double my_c = 0.0;
    for (int p = tid; p < PP; p += 1024) {
        int c = s_ct[p];
        unsigned long long key = s_key[p];
        bool sel = (c > 0) || (key >= kth);
        s_sel[p] = sel ? 1 : 0;
        if (sel) {
            if (c > 0) my_c += (double)ce[(size_t)b * PP + p];   // sparse
            else       my_c += (double)__uint_as_float((unsigned int)(key >> 32));
        }
    }
    __syncthreads();

    // Per-cell outputs
    for (int cI = tid; cI < CELLS; cI += 1024) {
        int mc = 0, hv = 0;
#pragma unroll
        for (int a = 0; a < 9; ++a) {
            int p = cI * 9 + a;
            int cv = s_ct[p];
            mc = (cv > mc) ? cv : mc;
            hv |= s_sel[p];
        }
        out[2 + (size_t)b * CELLS + cI] = (float)mc;
        out[2 + (size_t)BB * CELLS + (size_t)b * CELLS + cI] = (float)hv;
    }

#pragma unroll
    for (int off = 32; off > 0; off >>= 1) my_c += __shfl_down(my_c, off);
    if (lane == 0) s_part[wid] = my_c;
    __syncthreads();
    if (tid == 0) {
        double L = 0.0;
#pragma unroll
        for (int w2 = 0; w2 < 16; ++w2) L += s_part[w2];
        lossc[b] = L;
    }
}

__global__ __launch_bounds__(256) void finalize_kernel(
    const int* __restrict__ numpos, const double* __restrict__ lossl,
    const double* __restrict__ lossc, float* __restrict__ out)
{
    __shared__ double s_l[256], s_c[256];
    __shared__ int s_n[256];
    int tid = threadIdx.x;
    s_n[tid] = numpos[tid];     // BB == 256 == blockDim
    s_l[tid] = lossl[tid];
    s_c[tid] = lossc[tid];
    __syncthreads();
    for (int s = 128; s > 0; s >>= 1) {
        if (tid < s) { s_n[tid] += s_n[tid + s]; s_l[tid] += s_l[tid + s]; s_c[tid] += s_c[tid + s]; }
        __syncthreads();
    }
    if (tid == 0) {
        double N = (double)s_n[0];
        out[0] = (float)(s_l[0] / N);
        out[1] = (float)(s_c[0] / N);
    }
}

extern "C" void kernel_launch(void* const* d_in, const int* in_sizes, int n_in,
                              void* d_out, int out_size, void* d_ws, size_t ws_size,
                              hipStream_t stream) {
    const float* loc     = (const float*)d_in[0];  // (B, P, 4)
    const float* conf    = (const float*)d_in[1];  // (B, P, 21)
    const float* priors  = (const float*)d_in[2];  // (P, 4)
    const float* targets = (const float*)d_in[3];  // (B, 12, 5)
    float* out = (float*)d_out;

    // Workspace carve-up (8-byte aligned first)
    double* ws_lossl = (double*)d_ws;                 // BB
    double* ws_lossc = ws_lossl + BB;                 // BB
    int*    ws_numpos = (int*)(ws_lossc + BB);        // BB
    int*    ws_conf   = ws_numpos + BB;               // BB*PP
    float*  ws_ce     = (float*)(ws_conf + (size_t)BB * PP); // BB*PP

    hipLaunchKernelGGL(match_kernel, dim3(BB), dim3(1024), 0, stream,
                       loc, priors, targets, ws_conf, ws_numpos, ws_lossl);
    hipLaunchKernelGGL(ce_kernel, dim3(PP), dim3(256), 0, stream,
                       conf, ws_conf, ws_ce);
    hipLaunchKernelGGL(mine_kernel, dim3(BB), dim3(1024), 0, stream,
                       ws_conf, ws_ce, ws_numpos, ws_lossc, out);
    hipLaunchKernelGGL(finalize_kernel, dim3(1), dim3(256), 0, stream,
                       ws_numpos, ws_lossl, ws_lossc, out);
}

// Round 5
// 141.125 us; speedup vs baseline: 2.3386x; 1.0572x over previous
//
#include <hip/hip_runtime.h>
#include <math.h>

// Match numpy reference numerics exactly: no FMA contraction anywhere.
// Matching decisions (argmax ties, ov<0.5 threshold) rest on bit-exact floats.
#pragma clang fp contract(off)

#define BB      256
#define PP      3249         // 19*19*9
#define NCLS    21
#define NOBJ    12
#define CELLS   361          // 19*19
#define THRESH_ 0.5f

// d_out layout (float32): [0]=loss_l/N, [1]=loss_c/N,
// [2 .. 2+BB*CELLS) = conf_t_featuremap, [2+BB*CELLS .. 2+2*BB*CELLS) = have_centerloss

// ---------------------------------------------------------------------------
// Fully fused per-batch kernel: IoU matching + conf_t + smooth-L1 + inline CE
// + exact radix-select hard-negative mining + per-cell outputs. One block per
// batch, 1024 threads, everything block-local in LDS (~55 KB):
//   s_key  (26 KB): (ce_bits<<32)|~p  — mining keys, distinct, order == stable argsort
//   s_bov  (13 KB): pass1 best-overlap; reused in pass2 to hold TRUE CE per prior
//   s_bidx (6.5 KB), s_ct/s_sel (6.5 KB), s_hist (1 KB)
// conf is read with dword loads (batch row base is only 4B-aligned: b*272916 % 16 != 0).
// ---------------------------------------------------------------------------
__global__ __launch_bounds__(1024) void fused_kernel(
    const float* __restrict__ loc, const float* __restrict__ conf,
    const float* __restrict__ priors, const float* __restrict__ targets,
    int* __restrict__ numpos, double* __restrict__ lossl,
    double* __restrict__ lossc, float* __restrict__ out)
{
    const int b = blockIdx.x, tid = threadIdx.x;
    const int lane = tid & 63, wid = tid >> 6;   // 16 waves

    __shared__ float s_tx1[NOBJ], s_ty1[NOBJ], s_tx2[NOBJ], s_ty2[NOBJ];
    __shared__ float s_area_t[NOBJ];
    __shared__ int   s_label[NOBJ];
    __shared__ float s_bov[PP];                 // pass1: best ov; pass2+: true CE
    __shared__ short s_bidx[PP];
    __shared__ int   s_bpi[NOBJ];
    __shared__ float s_wov[NOBJ][16];
    __shared__ int   s_widx[NOBJ][16];
    __shared__ unsigned long long s_key[PP];
    __shared__ unsigned char s_ct[PP];
    __shared__ unsigned char s_sel[PP];
    __shared__ int s_hist[256];
    __shared__ int s_chosen, s_knext, s_nneg;
    __shared__ double s_pl[16];
    __shared__ int    s_pn[16];
    __shared__ double s_pc[16];

    if (tid < NOBJ) {
        const float* t = targets + ((size_t)b * NOBJ + tid) * 5;
        float x1 = t[0], y1 = t[1], x2 = t[2], y2 = t[3];
        s_tx1[tid] = x1; s_ty1[tid] = y1; s_tx2[tid] = x2; s_ty2[tid] = y2;
        s_label[tid] = (int)t[4];
        s_area_t[tid] = (x2 - x1) * (y2 - y1);
    }
    __syncthreads();

    // ---- Phase 1: IoU; per-prior best truth (first-max); per-truth best prior.
    float l_bov[NOBJ];
    int   l_bidx[NOBJ];
#pragma unroll
    for (int j = 0; j < NOBJ; ++j) { l_bov[j] = -1.0f; l_bidx[j] = 0x7FFFFFFF; }

    for (int p = tid; p < PP; p += 1024) {
        float cx = priors[4*p+0], cy = priors[4*p+1], w = priors[4*p+2], h = priors[4*p+3];
        float px1 = cx - w / 2.0f, py1 = cy - h / 2.0f;
        float px2 = cx + w / 2.0f, py2 = cy + h / 2.0f;
        float area_p = (px2 - px1) * (py2 - py1);
        float bov = -1.0f; int bidx = 0;
#pragma unroll
        for (int j = 0; j < NOBJ; ++j) {
            float ltx = fmaxf(s_tx1[j], px1);
            float lty = fmaxf(s_ty1[j], py1);
            float rbx = fminf(s_tx2[j], px2);
            float rby = fminf(s_ty2[j], py2);
            float iw = fmaxf(rbx - ltx, 0.0f);
            float ih = fmaxf(rby - lty, 0.0f);
            float inter = iw * ih;
            float iou = inter / ((s_area_t[j] + area_p) - inter);
            if (iou > bov) { bov = iou; bidx = j; }              // first max over truths
            if (iou > l_bov[j]) { l_bov[j] = iou; l_bidx[j] = p; } // best prior for truth j
        }
        s_bov[p] = bov;
        s_bidx[p] = (short)bidx;
    }

    // Wave butterfly reduce per-truth (max, ties -> smaller idx; associative).
#pragma unroll
    for (int j = 0; j < NOBJ; ++j) {
        float ov = l_bov[j]; int ix = l_bidx[j];
#pragma unroll
        for (int off = 32; off > 0; off >>= 1) {
            float ov2 = __shfl_xor(ov, off);
            int   ix2 = __shfl_xor(ix, off);
            if (ov2 > ov || (ov2 == ov && ix2 < ix)) { ov = ov2; ix = ix2; }
        }
        if (lane == 0) { s_wov[j][wid] = ov; s_widx[j][wid] = ix; }
    }
    __syncthreads();
    if (tid < NOBJ) {
        float ov = s_wov[tid][0]; int ix = s_widx[tid][0];
#pragma unroll
        for (int w2 = 1; w2 < 16; ++w2) {
            float ov2 = s_wov[tid][w2]; int ix2 = s_widx[tid][w2];
            if (ov2 > ov || (ov2 == ov && ix2 < ix)) { ov = ov2; ix = ix2; }
        }
        s_bpi[tid] = ix;
    }
    __syncthreads();

    // ---- Phase 2: conf_t + smooth-L1 + inline CE + mining keys.
    int my_pos = 0;
    double my_lossl = 0.0;
    const float* confb = conf + (size_t)b * PP * NCLS;
    for (int p = tid; p < PP; p += 1024) {
        int jov = -1;
#pragma unroll
        for (int j = 0; j < NOBJ; ++j) if (s_bpi[j] == p) jov = j;  // last-wins on duplicates
        int idx; float ov;
        if (jov >= 0) { idx = jov; ov = 2.0f; }
        else          { idx = (int)s_bidx[p]; ov = s_bov[p]; }
        int c = (ov < THRESH_) ? 0 : (s_label[idx] + 1);
        s_ct[p] = (unsigned char)c;

        // CE (op order identical to reference): dword reads, L1 absorbs reuse.
        const float* cd = confb + (size_t)p * NCLS;
        float m = cd[0];
#pragma unroll
        for (int k = 1; k < NCLS; ++k) m = fmaxf(m, cd[k]);
        float s = 0.0f;
#pragma unroll
        for (int k = 0; k < NCLS; ++k) s += expf(cd[k] - m);
        float ce = (logf(s) + m) - cd[c];

        float v = (c > 0) ? 0.0f : ce;          // mining value (pos compete as 0)
        s_key[p] = ((unsigned long long)__float_as_uint(v) << 32)
                 | (unsigned int)(0xFFFFFFFFu - (unsigned int)p);
        s_bov[p] = ce;                           // true CE (ov dead after read above)

        if (c > 0) {
            ++my_pos;
            float cx = priors[4*p+0], cy = priors[4*p+1], w = priors[4*p+2], h = priors[4*p+3];
            float m0 = s_tx1[idx], m1 = s_ty1[idx], m2 = s_tx2[idx], m3 = s_ty2[idx];
            float g0 = ((m0 + m2) / 2.0f - cx) / (0.1f * w);
            float g1 = ((m1 + m3) / 2.0f - cy) / (0.1f * h);
            float g2 = logf((m2 - m0) / w) / 0.2f;
            float g3 = logf((m3 - m1) / h) / 0.2f;
            const float* ld = loc + ((size_t)b * PP + p) * 4;
            float d0 = ld[0] - g0, d1 = ld[1] - g1, d2 = ld[2] - g2, d3 = ld[3] - g3;
            float a0 = fabsf(d0), a1 = fabsf(d1), a2 = fabsf(d2), a3 = fabsf(d3);
            my_lossl += (double)((a0 < 1.0f) ? 0.5f * d0 * d0 : a0 - 0.5f);
            my_lossl += (double)((a1 < 1.0f) ? 0.5f * d1 * d1 : a1 - 0.5f);
            my_lossl += (double)((a2 < 1.0f) ? 0.5f * d2 * d2 : a2 - 0.5f);
            my_lossl += (double)((a3 < 1.0f) ? 0.5f * d3 * d3 : a3 - 0.5f);
        }
    }
#pragma unroll
    for (int off = 32; off > 0; off >>= 1) {
        my_lossl += __shfl_down(my_lossl, off);
        my_pos   += __shfl_down(my_pos, off);
    }
    if (lane == 0) { s_pl[wid] = my_lossl; s_pn[wid] = my_pos; }
    __syncthreads();
    if (tid == 0) {
        double L = 0.0; int n = 0;
#pragma unroll
        for (int w2 = 0; w2 < 16; ++w2) { L += s_pl[w2]; n += s_pn[w2]; }
        lossl[b] = L; numpos[b] = n;
        s_nneg = min(3 * n, PP - 1);   // n >= 1 (forced matches)
    }
    __syncthreads();

    // ---- Phase 3: exact 8-bit radix select for the nneg-th largest key.
    unsigned long long prefix = 0ull, pmask = 0ull;
    int kk = s_nneg;
    for (int d = 56; d >= 0; d -= 8) {
        if (tid < 256) s_hist[tid] = 0;
        __syncthreads();
        for (int i = tid; i < PP; i += 1024) {
            unsigned long long key = s_key[i];
            if ((key & pmask) == prefix)
                atomicAdd(&s_hist[(int)((key >> d) & 0xFF)], 1);
        }
        __syncthreads();
        if (tid < 64) {   // wave 0: bin where top-down cumulative crosses kk
            int h0 = s_hist[4*lane+0], h1 = s_hist[4*lane+1];
            int h2 = s_hist[4*lane+2], h3 = s_hist[4*lane+3];
            int ls = h0 + h1 + h2 + h3;
            int x = ls;                       // inclusive suffix sum over lanes
#pragma unroll
            for (int off = 1; off < 64; off <<= 1) {
                int y = __shfl_down(x, off);
                if (lane + off < 64) x += y;
            }
            int excl = x - ls;                // sum over lanes > lane
            int cb3 = excl;
            int cb2 = cb3 + h3;
            int cb1 = cb2 + h2;
            int cb0 = cb1 + h1;
            if (cb3 < kk && kk <= cb3 + h3) { s_chosen = 4*lane+3; s_knext = kk - cb3; }
            if (cb2 < kk && kk <= cb2 + h2) { s_chosen = 4*lane+2; s_knext = kk - cb2; }
            if (cb1 < kk && kk <= cb1 + h1) { s_chosen = 4*lane+1; s_knext = kk - cb1; }
            if (cb0 < kk && kk <= cb0 + h0) { s_chosen = 4*lane+0; s_knext = kk - cb0; }
        }
        __syncthreads();
        prefix |= ((unsigned long long)(unsigned int)s_chosen) << d;
        pmask  |= 0xFFull << d;
        kk = s_knext;
        __syncthreads();   // protect s_chosen/s_knext before next round's writes
    }
    const unsigned long long kth = prefix;   // exact nneg-th largest key

    // ---- Phase 4: selection + loss_c (true CE lives in s_bov for all p).
    double my_c = 0.0;
    for (int p = tid; p < PP; p += 1024) {
        int c = s_ct[p];
        bool sel = (c > 0) || (s_key[p] >= kth);
        s_sel[p] = sel ? 1 : 0;
        if (sel) my_c += (double)s_bov[p];
    }
    __syncthreads();

    // ---- Phase 5: per-cell outputs.
    for (int cI = tid; cI < CELLS; cI += 1024) {
        int mc = 0, hv = 0;
#pragma unroll
        for (int a = 0; a < 9; ++a) {
            int p = cI * 9 + a;
            int cv = s_ct[p];
            mc = (cv > mc) ? cv : mc;
            hv |= s_sel[p];
        }
        out[2 + (size_t)b * CELLS + cI] = (float)mc;
        out[2 + (size_t)BB * CELLS + (size_t)b * CELLS + cI] = (float)hv;
    }

#pragma unroll
    for (int off = 32; off > 0; off >>= 1) my_c += __shfl_down(my_c, off);
    if (lane == 0) s_pc[wid] = my_c;
    __syncthreads();
    if (tid == 0) {
        double L = 0.0;
#pragma unroll
        for (int w2 = 0; w2 < 16; ++w2) L += s_pc[w2];
        lossc[b] = L;
    }
}

__global__ __launch_bounds__(256) void finalize_kernel(
    const int* __restrict__ numpos, const double* __restrict__ lossl,
    const double* __restrict__ lossc, float* __restrict__ out)
{
    __shared__ double s_l[256], s_c[256];
    __shared__ int s_n[256];
    int tid = threadIdx.x;
    s_n[tid] = numpos[tid];     // BB == 256 == blockDim
    s_l[tid] = lossl[tid];
    s_c[tid] = lossc[tid];
    __syncthreads();
    for (int s = 128; s > 0; s >>= 1) {
        if (tid < s) { s_n[tid] += s_n[tid + s]; s_l[tid] += s_l[tid + s]; s_c[tid] += s_c[tid + s]; }
        __syncthreads();
    }
    if (tid == 0) {
        double N = (double)s_n[0];
        out[0] = (float)(s_l[0] / N);
        out[1] = (float)(s_c[0] / N);
    }
}

extern "C" void kernel_launch(void* const* d_in, const int* in_sizes, int n_in,
                              void* d_out, int out_size, void* d_ws, size_t ws_size,
                              hipStream_t stream) {
    const float* loc     = (const float*)d_in[0];  // (B, P, 4)
    const float* conf    = (const float*)d_in[1];  // (B, P, 21)
    const float* priors  = (const float*)d_in[2];  // (P, 4)
    const float* targets = (const float*)d_in[3];  // (B, 12, 5)
    float* out = (float*)d_out;

    double* ws_lossl  = (double*)d_ws;             // BB
    double* ws_lossc  = ws_lossl + BB;             // BB
    int*    ws_numpos = (int*)(ws_lossc + BB);     // BB

    hipLaunchKernelGGL(fused_kernel, dim3(BB), dim3(1024), 0, stream,
                       loc, conf, priors, targets, ws_numpos, ws_lossl, ws_lossc, out);
    hipLaunchKernelGGL(finalize_kernel, dim3(1), dim3(256), 0, stream,
                       ws_numpos, ws_lossl, ws_lossc, out);
}